// Round 3
// baseline (188.828 us; speedup 1.0000x reference)
//
#include <hip/hip_runtime.h>

#define D 64
#define CAP 64

typedef unsigned short u16;
typedef unsigned int u32;
typedef short bf16x8 __attribute__((ext_vector_type(8)));
typedef float f32x4 __attribute__((ext_vector_type(4)));

__device__ __forceinline__ u16 f2bf(float f) {
    u32 u = __float_as_uint(f);
    return (u16)((u + 0x7FFFu + ((u >> 16) & 1u)) >> 16);   // RNE
}

// ---- X->bf16 convert + cnt zeroing + W/bias prepack + edge-record prepack ----
// R10: rec[e] = (bf16(ew[e])<<16)|src[e] built here with COALESCED reads so
// k_fill's divergent path no longer has dependent scattered scalar loads.
__global__ void k_prep(const float* __restrict__ X, u16* __restrict__ Xbf,
                       int* __restrict__ cnt, int n4, int N,
                       const int* __restrict__ ei, const float* __restrict__ ew,
                       u32* __restrict__ rec, int E,
                       const float* __restrict__ Wrel1, const float* __restrict__ Wroot1,
                       const float* __restrict__ Wrel3, const float* __restrict__ Wroot3,
                       const float* __restrict__ brel1, const float* __restrict__ broot1,
                       const float* __restrict__ brel2, const float* __restrict__ broot2,
                       const float* __restrict__ brel3, const float* __restrict__ broot3,
                       u16* __restrict__ Wpk, float* __restrict__ Bpk) {
    int i = blockIdx.x * blockDim.x + threadIdx.x;
    if (i < N) cnt[i] = 0;

    if (i < 2048) {           // W fragment prepack: 32 frags x 64 lanes
        int f    = i >> 6;    // ((stage*2+mat)*4+t)*2+kk
        int lane = i & 63;
        int stage = f >> 4, rest = f & 15;
        int mat = rest >> 3, t = (rest >> 1) & 3, kk = rest & 1;
        int ml = lane & 15, ql = lane >> 4;
        const float* W = stage ? (mat ? Wroot3 : Wrel3) : (mat ? Wroot1 : Wrel1);
        const float* src = W + (t * 16 + ml) * D + kk * 32 + ql * 8;
        union { u16 h[8]; uint4 v; } o;
#pragma unroll
        for (int e = 0; e < 8; ++e) o.h[e] = f2bf(src[e]);
        *reinterpret_cast<uint4*>(Wpk + (size_t)(f * 64 + lane) * 8) = o.v;
    }
    if (i < 128) {            // bias prepack
        int stage = i >> 6, c = i & 63;
        Bpk[i] = stage ? (brel3[c] + broot3[c])
                       : (brel1[c] + broot1[c] + brel2[c] + broot2[c]);
    }

    if (i < E)                // edge-record prepack (coalesced ew + src reads)
        rec[i] = (((u32)f2bf(ew[i])) << 16) | (u32)ei[i];

    if (i >= n4) return;
    float4 v = reinterpret_cast<const float4*>(X)[i];
    ushort4 o;
    o.x = f2bf(v.x); o.y = f2bf(v.y); o.z = f2bf(v.z); o.w = f2bf(v.w);
    reinterpret_cast<ushort4*>(Xbf)[i] = o;
}

// ---- XCD-partitioned bucket fill: coalesced dst+rec, atomic+store only ----
__global__ void k_fill(const int* __restrict__ ei, const u32* __restrict__ rec,
                       int* __restrict__ cnt, u32* __restrict__ pairs,
                       int E, int step) {
    const int g  = blockIdx.x & 7;
    const int b  = blockIdx.x >> 3;
    const int lo = g * step;
    const int hi = lo + step;
    const int nthr = (gridDim.x >> 3) * blockDim.x;
    const int t  = b * blockDim.x + threadIdx.x;
    const int nchunk = E >> 2;

    for (int c = t; c < nchunk; c += nthr) {
        int e = c * 4;
        int4  d4 = *reinterpret_cast<const int4*>(ei + E + e);
        uint4 r4 = *reinterpret_cast<const uint4*>(rec + e);
#define DO_EDGE(dd, rr)                                                          \
        if ((dd) >= lo && (dd) < hi) {                                           \
            int p = atomicAdd(cnt + (dd), 1);                                    \
            if (p < CAP) pairs[(dd) * CAP + p] = (rr);                           \
        }
        DO_EDGE(d4.x, r4.x)
        DO_EDGE(d4.y, r4.y)
        DO_EDGE(d4.z, r4.z)
        DO_EDGE(d4.w, r4.w)
#undef DO_EDGE
    }
    if (g == 0 && t == 0) {
        for (int e = nchunk * 4; e < E; ++e) {
            int d = ei[E + e];
            int p = atomicAdd(cnt + d, 1);
            if (p < CAP) pairs[d * CAP + p] = rec[e];
        }
    }
}

// ---- fused stage: 8-node strip, octet gather + MFMA + sigmoid ----
// R9: octet gather (lane o=lane>>3 owns node n0+o, uint4 = 8 channels), records
// broadcast from LDS (stride-68 rows, conflict-free), depth-3 rotation.
// R10: latency-bound, nothing saturated (VALU 35%, HBM 21%, occ 21%) ->
//  * __launch_bounds__(256,4): 16 waves/CU (was 12), +33% TLP
//  * W fragments loaded per-t inside the MFMA loop (epilogue peak was 64 VGPRs
//    of W; this keeps peak ~gather-phase ~100 < 128 cap, no spill)
template <int STAGE>
__global__ __launch_bounds__(256, 4) void k_stage(
        const u16* __restrict__ Gbf,
        const u16* __restrict__ Wpk,   // 16 frags x 64 lanes x 8 bf16 (this stage)
        const float* __restrict__ Bpk, // 64 floats (this stage)
        const int* __restrict__ cnt, const u32* __restrict__ pairs,
        float* __restrict__ outF, u16* __restrict__ outBf, int N) {
    __shared__ __align__(16) u16 smem[4 * 8 * 72];
    __shared__ __align__(16) u32 recs[4 * 8 * 68];   // stride 68: bank-spread + 16B-aligned
    const int lane = threadIdx.x & 63;
    const int wid  = threadIdx.x >> 6;
    const int ml   = lane & 15;
    const int ql   = lane >> 4;
    const int o    = lane >> 3;     // octet: owns node n0+o in gather
    const int c    = lane & 7;      // channel group: channels 8c..8c+7
    const int n0   = blockIdx.x * 32 + wid * 8;
    u16* sw = smem + wid * 8 * 72;
    u32* rw = recs + wid * 8 * 68;

    if (n0 >= N) return;   // waves independent, no barriers

    int cidx = n0 + (lane & 7); if (cidx >= N) cidx = N - 1;
    const int cnt8 = cnt[cidx];

    int deg[8], degmax = 0;
#pragma unroll
    for (int i = 0; i < 8; ++i) {
        int d = (n0 + i < N) ? __builtin_amdgcn_readlane(cnt8, i) : 0;
        if (d > CAP) d = CAP;
        deg[i] = d;
        degmax = degmax > d ? degmax : d;
    }

    // load records (slot = lane) and stage to LDS in octet-readable layout
#pragma unroll
    for (int i = 0; i < 8; ++i) {
        int r = n0 + i; if (r >= N) r = N - 1;
        u32 pv = (lane < deg[i]) ? pairs[(size_t)r * CAP + lane] : 0u;
        rw[i * 68 + lane] = pv;
    }

    const u32* prow  = rw + o * 68;          // this lane's node's record row
    const char* gbase = (const char*)Gbf;    // 128 B per row
    const int  c16   = c * 16;               // byte offset of lane's 8 channels

    float acc[8];
#pragma unroll
    for (int k = 0; k < 8; ++k) acc[k] = 0.f;

    uint4 rA, rB, rC;
    uint4 vA[4], vB[4], vC[4];
#define RECQ(rg, jj)  rg = *reinterpret_cast<const uint4*>(prow + (jj));
#define ISSUEV(vg, rg)                                                          \
    _Pragma("unroll") for (int s = 0; s < 4; ++s) {                             \
        u32 rec = (s == 0) ? (rg).x : (s == 1) ? (rg).y : (s == 2) ? (rg).z : (rg).w; \
        vg[s] = *reinterpret_cast<const uint4*>(                                \
            gbase + ((size_t)(rec & 0xFFFFu) << 7) + c16);                      \
    }
#define CONSUME(vg, rg)                                                         \
    _Pragma("unroll") for (int s = 0; s < 4; ++s) {                             \
        u32 rec = (s == 0) ? (rg).x : (s == 1) ? (rg).y : (s == 2) ? (rg).z : (rg).w; \
        float w  = __uint_as_float(rec & 0xFFFF0000u);                          \
        uint4 d  = vg[s];                                                       \
        acc[0] = fmaf(w, __uint_as_float(d.x << 16),         acc[0]);           \
        acc[1] = fmaf(w, __uint_as_float(d.x & 0xFFFF0000u), acc[1]);           \
        acc[2] = fmaf(w, __uint_as_float(d.y << 16),         acc[2]);           \
        acc[3] = fmaf(w, __uint_as_float(d.y & 0xFFFF0000u), acc[3]);           \
        acc[4] = fmaf(w, __uint_as_float(d.z << 16),         acc[4]);           \
        acc[5] = fmaf(w, __uint_as_float(d.z & 0xFFFF0000u), acc[5]);           \
        acc[6] = fmaf(w, __uint_as_float(d.w << 16),         acc[6]);           \
        acc[7] = fmaf(w, __uint_as_float(d.w & 0xFFFF0000u), acc[7]);           \
    }

    if (degmax > 0) {
        RECQ(rA, 0)
        ISSUEV(vA, rA)
        if (4 < degmax) { RECQ(rB, 4) ISSUEV(vB, rB) }
        int j = 0;
        for (;;) {
            if (j + 8 < degmax) { RECQ(rC, j + 8) ISSUEV(vC, rC) }
            CONSUME(vA, rA)
            j += 4;
            if (j >= degmax) break;
            if (j + 8 < degmax) { RECQ(rA, j + 8) ISSUEV(vA, rA) }
            CONSUME(vB, rB)
            j += 4;
            if (j >= degmax) break;
            if (j + 8 < degmax) { RECQ(rB, j + 8) ISSUEV(vB, rB) }
            CONSUME(vC, rC)
            j += 4;
            if (j >= degmax) break;
        }
    }
#undef RECQ
#undef ISSUEV
#undef CONSUME

    // acc -> LDS strip: lane holds channels 8c..8c+7 of node o
    {
        uint4 packed;
        packed.x = ((u32)f2bf(acc[1]) << 16) | (u32)f2bf(acc[0]);
        packed.y = ((u32)f2bf(acc[3]) << 16) | (u32)f2bf(acc[2]);
        packed.z = ((u32)f2bf(acc[5]) << 16) | (u32)f2bf(acc[4]);
        packed.w = ((u32)f2bf(acc[7]) << 16) | (u32)f2bf(acc[6]);
        *reinterpret_cast<uint4*>(sw + o * 72 + c * 8) = packed;  // 144B stride: 16B-aligned
    }

    // ---- A fragments: agg from LDS strip, root from global bf16 ----
    const int am = ml & 7;
    bf16x8 a_agg[2], a_x[2];
#pragma unroll
    for (int kk = 0; kk < 2; ++kk)
        a_agg[kk] = *reinterpret_cast<bf16x8*>(sw + am * 72 + kk * 32 + ql * 8);
    {
        int r = n0 + am; if (r >= N) r = N - 1;
#pragma unroll
        for (int kk = 0; kk < 2; ++kk)
            a_x[kk] = *reinterpret_cast<const bf16x8*>(Gbf + (size_t)r * D + kk * 32 + ql * 8);
    }

    // ---- MFMA + epilogue: W fragments loaded per-t (L2-hot, keeps VGPR low) ----
#pragma unroll
    for (int t = 0; t < 4; ++t) {
        int ch = t * 16 + ml;
        float bias = Bpk[ch];

        bf16x8 brel0  = *reinterpret_cast<const bf16x8*>(Wpk + (size_t)(((0 * 4 + t) * 2 + 0) * 64 + lane) * 8);
        bf16x8 brel1  = *reinterpret_cast<const bf16x8*>(Wpk + (size_t)(((0 * 4 + t) * 2 + 1) * 64 + lane) * 8);
        bf16x8 broot0 = *reinterpret_cast<const bf16x8*>(Wpk + (size_t)(((1 * 4 + t) * 2 + 0) * 64 + lane) * 8);
        bf16x8 broot1 = *reinterpret_cast<const bf16x8*>(Wpk + (size_t)(((1 * 4 + t) * 2 + 1) * 64 + lane) * 8);

        f32x4 accv = {0.f, 0.f, 0.f, 0.f};
        accv = __builtin_amdgcn_mfma_f32_16x16x32_bf16(a_agg[0], brel0,  accv, 0, 0, 0);
        accv = __builtin_amdgcn_mfma_f32_16x16x32_bf16(a_agg[1], brel1,  accv, 0, 0, 0);
        accv = __builtin_amdgcn_mfma_f32_16x16x32_bf16(a_x[0],   broot0, accv, 0, 0, 0);
        accv = __builtin_amdgcn_mfma_f32_16x16x32_bf16(a_x[1],   broot1, accv, 0, 0, 0);
        if (ql < 2) {                       // strip rows 0..7 only
#pragma unroll
            for (int r = 0; r < 4; ++r) {
                int row = n0 + ql * 4 + r;  // C/D: row=(lane>>4)*4+reg, col=lane&15
                if (row < N) {
                    float z = accv[r] + bias;
                    float h = 1.f / (1.f + __expf(-z));
                    int off = row * D + ch;
                    if (STAGE == 1) outBf[off] = f2bf(h);
                    else            outF[off]  = h;
                }
            }
        }
    }
}

extern "C" void kernel_launch(void* const* d_in, const int* in_sizes, int n_in,
                              void* d_out, int out_size, void* d_ws, size_t ws_size,
                              hipStream_t stream) {
    const float* X      = (const float*)d_in[0];
    const int*   ei     = (const int*)  d_in[1];
    const float* ew     = (const float*)d_in[2];
    const float* Wrel1  = (const float*)d_in[3];
    const float* brel1  = (const float*)d_in[4];
    const float* Wroot1 = (const float*)d_in[5];
    const float* broot1 = (const float*)d_in[6];
    // d_in[7], d_in[9] (Wrel2, Wroot2) multiply H_prev==0 -> unused
    const float* brel2  = (const float*)d_in[8];
    const float* broot2 = (const float*)d_in[10];
    const float* Wrel3  = (const float*)d_in[11];
    const float* brel3  = (const float*)d_in[12];
    const float* Wroot3 = (const float*)d_in[13];
    const float* broot3 = (const float*)d_in[14];

    const int N = in_sizes[0] / D;
    const int E = in_sizes[1] / 2;

    char* ws = (char*)d_ws;
    int* cnt = (int*)ws;
    size_t off = (((size_t)N * 4) + 255) & ~(size_t)255;
    u32* pairs = (u32*)(ws + off);        off += (size_t)N * CAP * 4;
    u16* Xbf   = (u16*)(ws + off);        off += (size_t)N * D * 2;
    u16* Hbf   = (u16*)(ws + off);        off += (size_t)N * D * 2;
    u16* Wpk   = (u16*)(ws + off);        off += (size_t)32 * 64 * 8 * 2;
    float* Bpk = (float*)(ws + off);      off += 512;
    u32* rec   = (u32*)(ws + off);        off += (size_t)E * 4;

    {
        int n4 = N * D / 4;
        int T  = n4 > N ? n4 : N;
        if (E > T) T = E;
        k_prep<<<(T + 255) / 256, 256, 0, stream>>>(
            X, Xbf, cnt, n4, N, ei, ew, rec, E,
            Wrel1, Wroot1, Wrel3, Wroot3,
            brel1, broot1, brel2, broot2, brel3, broot3, Wpk, Bpk);
    }
    {
        int step = (N + 7) / 8;
        k_fill<<<1600, 256, 0, stream>>>(ei, rec, cnt, pairs, E, step);
    }

    const int NB = (N + 31) / 32;
    k_stage<1><<<NB, 256, 0, stream>>>(Xbf, Wpk, Bpk,
                                       cnt, pairs, nullptr, Hbf, N);
    k_stage<2><<<NB, 256, 0, stream>>>(Hbf, Wpk + 16 * 64 * 8, Bpk + 64,
                                       cnt, pairs, (float*)d_out, nullptr, N);
}

// Round 4
// 182.603 us; speedup vs baseline: 1.0341x; 1.0341x over previous
//
#include <hip/hip_runtime.h>

#define D 64
#define CAP 64

typedef unsigned short u16;
typedef unsigned int u32;
typedef short bf16x8 __attribute__((ext_vector_type(8)));
typedef float f32x4 __attribute__((ext_vector_type(4)));

__device__ __forceinline__ u16 f2bf(float f) {
    u32 u = __float_as_uint(f);
    return (u16)((u + 0x7FFFu + ((u >> 16) & 1u)) >> 16);   // RNE
}

// ---- X->bf16 convert + cnt zeroing + W/bias prepack + edge-record prepack ----
__global__ void k_prep(const float* __restrict__ X, u16* __restrict__ Xbf,
                       int* __restrict__ cnt, int n4, int N,
                       const int* __restrict__ ei, const float* __restrict__ ew,
                       u32* __restrict__ rec, int E,
                       const float* __restrict__ Wrel1, const float* __restrict__ Wroot1,
                       const float* __restrict__ Wrel3, const float* __restrict__ Wroot3,
                       const float* __restrict__ brel1, const float* __restrict__ broot1,
                       const float* __restrict__ brel2, const float* __restrict__ broot2,
                       const float* __restrict__ brel3, const float* __restrict__ broot3,
                       u16* __restrict__ Wpk, float* __restrict__ Bpk) {
    int i = blockIdx.x * blockDim.x + threadIdx.x;
    if (i < N) cnt[i] = 0;

    if (i < 2048) {           // W fragment prepack: 32 frags x 64 lanes
        int f    = i >> 6;    // ((stage*2+mat)*4+t)*2+kk
        int lane = i & 63;
        int stage = f >> 4, rest = f & 15;
        int mat = rest >> 3, t = (rest >> 1) & 3, kk = rest & 1;
        int ml = lane & 15, ql = lane >> 4;
        const float* W = stage ? (mat ? Wroot3 : Wrel3) : (mat ? Wroot1 : Wrel1);
        const float* src = W + (t * 16 + ml) * D + kk * 32 + ql * 8;
        union { u16 h[8]; uint4 v; } o;
#pragma unroll
        for (int e = 0; e < 8; ++e) o.h[e] = f2bf(src[e]);
        *reinterpret_cast<uint4*>(Wpk + (size_t)(f * 64 + lane) * 8) = o.v;
    }
    if (i < 128) {            // bias prepack
        int stage = i >> 6, c = i & 63;
        Bpk[i] = stage ? (brel3[c] + broot3[c])
                       : (brel1[c] + broot1[c] + brel2[c] + broot2[c]);
    }

    if (i < E)                // edge-record prepack (coalesced ew + src reads)
        rec[i] = (((u32)f2bf(ew[i])) << 16) | (u32)ei[i];

    if (i >= n4) return;
    float4 v = reinterpret_cast<const float4*>(X)[i];
    ushort4 o;
    o.x = f2bf(v.x); o.y = f2bf(v.y); o.z = f2bf(v.z); o.w = f2bf(v.w);
    reinterpret_cast<ushort4*>(Xbf)[i] = o;
}

// ---- XCD-partitioned bucket fill: coalesced dst+rec, atomic+store only ----
__global__ void k_fill(const int* __restrict__ ei, const u32* __restrict__ rec,
                       int* __restrict__ cnt, u32* __restrict__ pairs,
                       int E, int step) {
    const int g  = blockIdx.x & 7;
    const int b  = blockIdx.x >> 3;
    const int lo = g * step;
    const int hi = lo + step;
    const int nthr = (gridDim.x >> 3) * blockDim.x;
    const int t  = b * blockDim.x + threadIdx.x;
    const int nchunk = E >> 2;

    for (int c = t; c < nchunk; c += nthr) {
        int e = c * 4;
        int4  d4 = *reinterpret_cast<const int4*>(ei + E + e);
        uint4 r4 = *reinterpret_cast<const uint4*>(rec + e);
#define DO_EDGE(dd, rr)                                                          \
        if ((dd) >= lo && (dd) < hi) {                                           \
            int p = atomicAdd(cnt + (dd), 1);                                    \
            if (p < CAP) pairs[(dd) * CAP + p] = (rr);                           \
        }
        DO_EDGE(d4.x, r4.x)
        DO_EDGE(d4.y, r4.y)
        DO_EDGE(d4.z, r4.z)
        DO_EDGE(d4.w, r4.w)
#undef DO_EDGE
    }
    if (g == 0 && t == 0) {
        for (int e = nchunk * 4; e < E; ++e) {
            int d = ei[E + e];
            int p = atomicAdd(cnt + d, 1);
            if (p < CAP) pairs[d * CAP + p] = rec[e];
        }
    }
}

// ---- fused stage: 8-node strip, octet gather + MFMA + sigmoid ----
// R9: octet gather (lane o=lane>>3 owns node n0+o, uint4 = 8 channels), records
// broadcast from LDS (stride-68 rows, conflict-free), depth-3 rotation.
// R10: (256,4) occupancy + per-t W loads (neutral -> gather is service-bound).
// R11: epilogue store coalescing. R1 counters showed WRITE_SIZE 29.7MB/stage vs
// 6.4/12.8 ideal (partial-line scalar u16/f32 stores -> write-allocate RMW, and
// ~512 TA-serialized store insts/wave). Now: MFMA results staged in LDS (sw
// strip for stage1 bf16, dead recs area for stage2 f32), then ONE (stage1) or
// TWO (stage2) coalesced 1KB uint4 stores per wave. Bit-identical math.
template <int STAGE>
__global__ __launch_bounds__(256, 4) void k_stage(
        const u16* __restrict__ Gbf,
        const u16* __restrict__ Wpk,   // 16 frags x 64 lanes x 8 bf16 (this stage)
        const float* __restrict__ Bpk, // 64 floats (this stage)
        const int* __restrict__ cnt, const u32* __restrict__ pairs,
        float* __restrict__ outF, u16* __restrict__ outBf, int N) {
    __shared__ __align__(16) u16 smem[4 * 8 * 72];
    __shared__ __align__(16) u32 recs[4 * 8 * 68];   // stride 68: bank-spread + 16B-aligned
    const int lane = threadIdx.x & 63;
    const int wid  = threadIdx.x >> 6;
    const int ml   = lane & 15;
    const int ql   = lane >> 4;
    const int o    = lane >> 3;     // octet: owns node n0+o in gather
    const int c    = lane & 7;      // channel group: channels 8c..8c+7
    const int n0   = blockIdx.x * 32 + wid * 8;
    u16* sw = smem + wid * 8 * 72;
    u32* rw = recs + wid * 8 * 68;

    if (n0 >= N) return;   // waves independent, no barriers

    int cidx = n0 + (lane & 7); if (cidx >= N) cidx = N - 1;
    const int cnt8 = cnt[cidx];

    int deg[8], degmax = 0;
#pragma unroll
    for (int i = 0; i < 8; ++i) {
        int d = (n0 + i < N) ? __builtin_amdgcn_readlane(cnt8, i) : 0;
        if (d > CAP) d = CAP;
        deg[i] = d;
        degmax = degmax > d ? degmax : d;
    }

    // load records (slot = lane) and stage to LDS in octet-readable layout
#pragma unroll
    for (int i = 0; i < 8; ++i) {
        int r = n0 + i; if (r >= N) r = N - 1;
        u32 pv = (lane < deg[i]) ? pairs[(size_t)r * CAP + lane] : 0u;
        rw[i * 68 + lane] = pv;
    }

    const u32* prow  = rw + o * 68;          // this lane's node's record row
    const char* gbase = (const char*)Gbf;    // 128 B per row
    const int  c16   = c * 16;               // byte offset of lane's 8 channels

    float acc[8];
#pragma unroll
    for (int k = 0; k < 8; ++k) acc[k] = 0.f;

    uint4 rA, rB, rC;
    uint4 vA[4], vB[4], vC[4];
#define RECQ(rg, jj)  rg = *reinterpret_cast<const uint4*>(prow + (jj));
#define ISSUEV(vg, rg)                                                          \
    _Pragma("unroll") for (int s = 0; s < 4; ++s) {                             \
        u32 rec = (s == 0) ? (rg).x : (s == 1) ? (rg).y : (s == 2) ? (rg).z : (rg).w; \
        vg[s] = *reinterpret_cast<const uint4*>(                                \
            gbase + ((size_t)(rec & 0xFFFFu) << 7) + c16);                      \
    }
#define CONSUME(vg, rg)                                                         \
    _Pragma("unroll") for (int s = 0; s < 4; ++s) {                             \
        u32 rec = (s == 0) ? (rg).x : (s == 1) ? (rg).y : (s == 2) ? (rg).z : (rg).w; \
        float w  = __uint_as_float(rec & 0xFFFF0000u);                          \
        uint4 d  = vg[s];                                                       \
        acc[0] = fmaf(w, __uint_as_float(d.x << 16),         acc[0]);           \
        acc[1] = fmaf(w, __uint_as_float(d.x & 0xFFFF0000u), acc[1]);           \
        acc[2] = fmaf(w, __uint_as_float(d.y << 16),         acc[2]);           \
        acc[3] = fmaf(w, __uint_as_float(d.y & 0xFFFF0000u), acc[3]);           \
        acc[4] = fmaf(w, __uint_as_float(d.z << 16),         acc[4]);           \
        acc[5] = fmaf(w, __uint_as_float(d.z & 0xFFFF0000u), acc[5]);           \
        acc[6] = fmaf(w, __uint_as_float(d.w << 16),         acc[6]);           \
        acc[7] = fmaf(w, __uint_as_float(d.w & 0xFFFF0000u), acc[7]);           \
    }

    if (degmax > 0) {
        RECQ(rA, 0)
        ISSUEV(vA, rA)
        if (4 < degmax) { RECQ(rB, 4) ISSUEV(vB, rB) }
        int j = 0;
        for (;;) {
            if (j + 8 < degmax) { RECQ(rC, j + 8) ISSUEV(vC, rC) }
            CONSUME(vA, rA)
            j += 4;
            if (j >= degmax) break;
            if (j + 8 < degmax) { RECQ(rA, j + 8) ISSUEV(vA, rA) }
            CONSUME(vB, rB)
            j += 4;
            if (j >= degmax) break;
            if (j + 8 < degmax) { RECQ(rB, j + 8) ISSUEV(vB, rB) }
            CONSUME(vC, rC)
            j += 4;
            if (j >= degmax) break;
        }
    }
#undef RECQ
#undef ISSUEV
#undef CONSUME

    // acc -> LDS strip: lane holds channels 8c..8c+7 of node o
    {
        uint4 packed;
        packed.x = ((u32)f2bf(acc[1]) << 16) | (u32)f2bf(acc[0]);
        packed.y = ((u32)f2bf(acc[3]) << 16) | (u32)f2bf(acc[2]);
        packed.z = ((u32)f2bf(acc[5]) << 16) | (u32)f2bf(acc[4]);
        packed.w = ((u32)f2bf(acc[7]) << 16) | (u32)f2bf(acc[6]);
        *reinterpret_cast<uint4*>(sw + o * 72 + c * 8) = packed;  // 144B stride: 16B-aligned
    }

    // ---- A fragments: agg from LDS strip, root from global bf16 ----
    const int am = ml & 7;
    bf16x8 a_agg[2], a_x[2];
#pragma unroll
    for (int kk = 0; kk < 2; ++kk)
        a_agg[kk] = *reinterpret_cast<bf16x8*>(sw + am * 72 + kk * 32 + ql * 8);
    {
        int r = n0 + am; if (r >= N) r = N - 1;
#pragma unroll
        for (int kk = 0; kk < 2; ++kk)
            a_x[kk] = *reinterpret_cast<const bf16x8*>(Gbf + (size_t)r * D + kk * 32 + ql * 8);
    }

    // f32 staging for STAGE==2 reuses the (dead) record area: [8][64] f32 = 2048B
    float* fst = (float*)rw;

    // ---- MFMA + epilogue: W per-t (L2-hot); results -> LDS, coalesced store ----
#pragma unroll
    for (int t = 0; t < 4; ++t) {
        int ch = t * 16 + ml;
        float bias = Bpk[ch];

        bf16x8 brel0  = *reinterpret_cast<const bf16x8*>(Wpk + (size_t)(((0 * 4 + t) * 2 + 0) * 64 + lane) * 8);
        bf16x8 brel1  = *reinterpret_cast<const bf16x8*>(Wpk + (size_t)(((0 * 4 + t) * 2 + 1) * 64 + lane) * 8);
        bf16x8 broot0 = *reinterpret_cast<const bf16x8*>(Wpk + (size_t)(((1 * 4 + t) * 2 + 0) * 64 + lane) * 8);
        bf16x8 broot1 = *reinterpret_cast<const bf16x8*>(Wpk + (size_t)(((1 * 4 + t) * 2 + 1) * 64 + lane) * 8);

        f32x4 accv = {0.f, 0.f, 0.f, 0.f};
        accv = __builtin_amdgcn_mfma_f32_16x16x32_bf16(a_agg[0], brel0,  accv, 0, 0, 0);
        accv = __builtin_amdgcn_mfma_f32_16x16x32_bf16(a_agg[1], brel1,  accv, 0, 0, 0);
        accv = __builtin_amdgcn_mfma_f32_16x16x32_bf16(a_x[0],   broot0, accv, 0, 0, 0);
        accv = __builtin_amdgcn_mfma_f32_16x16x32_bf16(a_x[1],   broot1, accv, 0, 0, 0);
        if (ql < 2) {                       // strip rows 0..7 only
#pragma unroll
            for (int r = 0; r < 4; ++r) {
                int row = ql * 4 + r;       // C/D: row=(lane>>4)*4+reg, col=lane&15
                float z = accv[r] + bias;
                float h = 1.f / (1.f + __expf(-z));
                if (STAGE == 1) sw[row * 72 + ch]  = f2bf(h);   // bf16 staging
                else            fst[row * 64 + ch] = h;         // f32 staging
            }
        }
    }

    // ---- coalesced output: 1KB (stage1) / 2KB (stage2) per wave ----
    if (STAGE == 1) {
        int row = lane >> 3;                 // lane covers 16B of row (lane>>3)
        if (n0 + row < N) {
            uint4 v = *reinterpret_cast<const uint4*>(sw + row * 72 + (lane & 7) * 8);
            *reinterpret_cast<uint4*>(outBf + (size_t)(n0 + row) * D + (lane & 7) * 8) = v;
        }
    } else {
        int r0 = lane >> 4;                  // first store: rows 0..3
        {
            uint4 v = reinterpret_cast<const uint4*>(fst)[lane];
            if (n0 + r0 < N)
                reinterpret_cast<uint4*>(outF + (size_t)(n0 + r0) * D)[lane & 15] = v;
        }
        {
            uint4 v = reinterpret_cast<const uint4*>(fst)[64 + lane];  // rows 4..7
            if (n0 + 4 + r0 < N)
                reinterpret_cast<uint4*>(outF + (size_t)(n0 + 4 + r0) * D)[lane & 15] = v;
        }
    }
}

extern "C" void kernel_launch(void* const* d_in, const int* in_sizes, int n_in,
                              void* d_out, int out_size, void* d_ws, size_t ws_size,
                              hipStream_t stream) {
    const float* X      = (const float*)d_in[0];
    const int*   ei     = (const int*)  d_in[1];
    const float* ew     = (const float*)d_in[2];
    const float* Wrel1  = (const float*)d_in[3];
    const float* brel1  = (const float*)d_in[4];
    const float* Wroot1 = (const float*)d_in[5];
    const float* broot1 = (const float*)d_in[6];
    // d_in[7], d_in[9] (Wrel2, Wroot2) multiply H_prev==0 -> unused
    const float* brel2  = (const float*)d_in[8];
    const float* broot2 = (const float*)d_in[10];
    const float* Wrel3  = (const float*)d_in[11];
    const float* brel3  = (const float*)d_in[12];
    const float* Wroot3 = (const float*)d_in[13];
    const float* broot3 = (const float*)d_in[14];

    const int N = in_sizes[0] / D;
    const int E = in_sizes[1] / 2;

    char* ws = (char*)d_ws;
    int* cnt = (int*)ws;
    size_t off = (((size_t)N * 4) + 255) & ~(size_t)255;
    u32* pairs = (u32*)(ws + off);        off += (size_t)N * CAP * 4;
    u16* Xbf   = (u16*)(ws + off);        off += (size_t)N * D * 2;
    u16* Hbf   = (u16*)(ws + off);        off += (size_t)N * D * 2;
    u16* Wpk   = (u16*)(ws + off);        off += (size_t)32 * 64 * 8 * 2;
    float* Bpk = (float*)(ws + off);      off += 512;
    u32* rec   = (u32*)(ws + off);        off += (size_t)E * 4;

    {
        int n4 = N * D / 4;
        int T  = n4 > N ? n4 : N;
        if (E > T) T = E;
        k_prep<<<(T + 255) / 256, 256, 0, stream>>>(
            X, Xbf, cnt, n4, N, ei, ew, rec, E,
            Wrel1, Wroot1, Wrel3, Wroot3,
            brel1, broot1, brel2, broot2, brel3, broot3, Wpk, Bpk);
    }
    {
        int step = (N + 7) / 8;
        k_fill<<<1600, 256, 0, stream>>>(ei, rec, cnt, pairs, E, step);
    }

    const int NB = (N + 31) / 32;
    k_stage<1><<<NB, 256, 0, stream>>>(Xbf, Wpk, Bpk,
                                       cnt, pairs, nullptr, Hbf, N);
    k_stage<2><<<NB, 256, 0, stream>>>(Hbf, Wpk + 16 * 64 * 8, Bpk + 64,
                                       cnt, pairs, (float*)d_out, nullptr, N);
}